// Round 8
// baseline (208.119 us; speedup 1.0000x reference)
//
#include <hip/hip_runtime.h>
#include <math.h>

typedef __attribute__((ext_vector_type(8))) short bf16x8;
typedef __attribute__((ext_vector_type(4))) float f32x4;

// ================= compile-time Clebsch-Gordan tables =================
constexpr double cfact(int n){ double r=1.0; for(int i=2;i<=n;++i) r*=(double)i; return r; }
constexpr double csqrt_(double x){ double g=(x>1.0)?x:1.0; for(int i=0;i<100;++i) g=0.5*(g+x/g); return g; }
constexpr double cg_coef_(int l1,int m1,int l2,int m2,int l,int m){
  double pre = csqrt_((double)(2*l+1)*cfact(l1+l2-l)*cfact(l1-l2+l)*cfact(-l1+l2+l)/cfact(l1+l2+l+1));
  pre = pre*csqrt_(cfact(l+m)*cfact(l-m)*cfact(l1-m1)*cfact(l1+m1)*cfact(l2-m2)*cfact(l2+m2));
  double s=0.0;
  for(int k=0;k<=l1+l2-l;++k){
    int d0=k,d1=l1+l2-l-k,d2=l1-m1-k,d3=l2+m2-k,d4=l-l2+m1+k,d5=l-l1-m2+k;
    if(d0<0||d1<0||d2<0||d3<0||d4<0||d5<0) continue;
    double den=cfact(d0)*cfact(d1)*cfact(d2)*cfact(d3)*cfact(d4)*cfact(d5);
    s+=((k&1)?-1.0:1.0)/den;
  }
  return pre*s;
}
struct CGList{ int n; float coef[64]; int mi[64]; int ni[64]; int pi[64]; };
constexpr CGList build_cg(int l1,int l2,int l){
  CGList T{};
  for(int i=0;i<2*l1+1;++i){
    for(int j=0;j<2*l2+1;++j){
      int m1=i-l1, m2=j-l2, m=m1+m2;
      if(m<-l||m>l) continue;
      double c=cg_coef_(l1,m1,l2,m2,l,m);
      if(c>1e-12||c<-1e-12){
        T.coef[T.n]=(float)c; T.mi[T.n]=i; T.ni[T.n]=j; T.pi[T.n]=m+l; T.n++;
      }
    }
  }
  return T;
}

// ================= layout constants =================
__device__ __host__ constexpr int AOFF(int l){ return l==0?0: l==1?16: l==2?64:144; }
__device__ __host__ constexpr int MLs(int l){ return l==0?1024: l==1?1536: l==2?1792:1536; }
__device__ __host__ constexpr int WOFF(int l){ return l==0?0: l==1?16384: l==2?40960:69632; }
__device__ __host__ constexpr int SOFF(int l){ return l==0?0: l==1?1024: l==2?2560:4352; }
__device__ __host__ constexpr int NTRI(int l){ return l==0?4: l==1?6: l==2?7:6; }
__device__ __host__ constexpr int ABASE(int l){ return l==0?0: l==1?65536: l==2?163840:278528; }
// mid storage (TILED): per-l base in 4B words. Layout within l:
//   word = nt*(Ml*16) + (c>>4)*256 + ((c>>2)&3)*64 + (n&15)*4 + (c&3)
// where n = b*NP+p (row), c = word-channel index. A wave's B-fragment for
// K-chunk kk is then one contiguous 1024B block at nt*(Ml*16)+kk*256+lane*4.
__device__ __host__ constexpr size_t MBW(int l){ return l==0?0 : l==1?2097152 : l==2?11534336 : 29884416; }
#define MID_OFF 1048576
#define MID_BYTES ((size_t)51904512*4)

#define DEVFN __device__ __forceinline__
#define LPITCH 144   // fallback-path LDS pitch

DEVFN unsigned f2bf2(float x, float y){
  unsigned ux = __float_as_uint(x); ux = (ux + 0x7FFFu + ((ux>>16)&1u)) >> 16;
  unsigned uy = __float_as_uint(y); uy = (uy + 0x7FFFu + ((uy>>16)&1u)) >> 16;
  return (ux & 0xFFFFu) | (uy << 16);
}

template<int L1,int L2,int L>
DEVFN void cg_accum(const float2* F1, const float2* F2, float2* mid){
  constexpr CGList T = build_cg(L1,L2,L);
  #pragma unroll
  for(int e=0;e<T.n;++e){
    const float c = T.coef[e];
    const float2 a = F1[T.mi[e]];
    const float2 b = F2[T.ni[e]];
    float pr = a.x*b.x - a.y*b.y;
    float pim= a.x*b.y + a.y*b.x;
    mid[T.pi[e]].x += c*pr;
    mid[T.pi[e]].y += c*pim;
  }
}

// ===== K1: LDS-staged act; channels (2u,2u+1) share F1; tiled mid stores =====
template<int L1,int L2,int L,int Q>
DEVFN void k1_body(const float2* __restrict__ acts, int b0, int u, int bh,
                   float& ssa, float& ssb, unsigned* __restrict__ midw){
  constexpr int N1=2*L1+1, N2=2*L2+1, NP=2*L+1, Ml=MLs(L);
  const int t = u>>3, s0 = (u&7)*2;
  unsigned* midl = midw ? (midw + MBW(L)) : nullptr;
  const int cg = Q*256 + 2*u;                       // even word-channel index
  const int koff = (cg>>4)*256 + ((cg>>2)&3)*64 + (cg&3);  // thread-const
  #pragma unroll 2
  for(int bi=0;bi<8;++bi){
    const int row = bh*8 + bi;
    const float2* arow = acts + row*256;
    float2 F1[N1], F2a[N2], F2b[N2], mida[NP], midb[NP];
    #pragma unroll
    for(int m=0;m<N1;++m) F1[m]=arow[AOFF(L1)+t*N1+m];
    #pragma unroll
    for(int n=0;n<N2;++n){
      F2a[n]=arow[AOFF(L2)+s0*N2+n];
      F2b[n]=arow[AOFF(L2)+(s0+1)*N2+n];
    }
    #pragma unroll
    for(int p=0;p<NP;++p){ mida[p]=make_float2(0.f,0.f); midb[p]=make_float2(0.f,0.f); }
    cg_accum<L1,L2,L>(F1,F2a,mida);
    cg_accum<L1,L2,L>(F1,F2b,midb);
    #pragma unroll
    for(int p=0;p<NP;++p){
      ssa += mida[p].x*mida[p].x + mida[p].y*mida[p].y;
      ssb += midb[p].x*midb[p].x + midb[p].y*midb[p].y;
    }
    if(midl){
      const size_t nbase = (size_t)(b0+row)*NP;
      #pragma unroll
      for(int p=0;p<NP;++p){
        const size_t n = nbase + p;
        uint2 v; v.x = f2bf2(mida[p].x, mida[p].y); v.y = f2bf2(midb[p].x, midb[p].y);
        *(uint2*)(midl + (n>>4)*((size_t)Ml*16) + (n&15)*4 + koff) = v;
      }
    }
  }
}

__global__ __launch_bounds__(256) void k_sumsq(const float* __restrict__ act,
                                               float* __restrict__ sumsq,
                                               unsigned* __restrict__ midw){
  __shared__ float2 acts[16*256];            // 32 KB: 16 act rows
  int bid=blockIdx.x;                        // 23 triples * 128 chunks
  // heavy triples dispatched first (CG-nonzero-count descending)
  const int order[23] = {22,16,21,18,15,20,13,9,14,8,17,7,12,6,10,3,5,19,2,11,1,4,0};
  int ti = order[bid>>7];
  int b0 = (bid&127)*16;
  const int tid = threadIdx.x;
  {
    const float4* ag = (const float4*)act + (size_t)b0*128;
    float4* as4 = (float4*)acts;
    #pragma unroll
    for(int j=0;j<8;++j) as4[j*256+tid] = ag[j*256+tid];
  }
  __syncthreads();
  const int u = tid & 127, bh = tid >> 7;    // channels (2u,2u+1), b-half bh
  float ssa=0.f, ssb=0.f;
  switch(ti){
    case 0:  k1_body<0,0,0,0>(acts,b0,u,bh,ssa,ssb,midw); break;
    case 1:  k1_body<1,1,0,1>(acts,b0,u,bh,ssa,ssb,midw); break;
    case 2:  k1_body<2,2,0,2>(acts,b0,u,bh,ssa,ssb,midw); break;
    case 3:  k1_body<3,3,0,3>(acts,b0,u,bh,ssa,ssb,midw); break;
    case 4:  k1_body<1,0,1,0>(acts,b0,u,bh,ssa,ssb,midw); break;
    case 5:  k1_body<1,1,1,1>(acts,b0,u,bh,ssa,ssb,midw); break;
    case 6:  k1_body<2,1,1,2>(acts,b0,u,bh,ssa,ssb,midw); break;
    case 7:  k1_body<2,2,1,3>(acts,b0,u,bh,ssa,ssb,midw); break;
    case 8:  k1_body<3,2,1,4>(acts,b0,u,bh,ssa,ssb,midw); break;
    case 9:  k1_body<3,3,1,5>(acts,b0,u,bh,ssa,ssb,midw); break;
    case 10: k1_body<1,1,2,0>(acts,b0,u,bh,ssa,ssb,midw); break;
    case 11: k1_body<2,0,2,1>(acts,b0,u,bh,ssa,ssb,midw); break;
    case 12: k1_body<2,1,2,2>(acts,b0,u,bh,ssa,ssb,midw); break;
    case 13: k1_body<2,2,2,3>(acts,b0,u,bh,ssa,ssb,midw); break;
    case 14: k1_body<3,1,2,4>(acts,b0,u,bh,ssa,ssb,midw); break;
    case 15: k1_body<3,2,2,5>(acts,b0,u,bh,ssa,ssb,midw); break;
    case 16: k1_body<3,3,2,6>(acts,b0,u,bh,ssa,ssb,midw); break;
    case 17: k1_body<2,1,3,0>(acts,b0,u,bh,ssa,ssb,midw); break;
    case 18: k1_body<2,2,3,1>(acts,b0,u,bh,ssa,ssb,midw); break;
    case 19: k1_body<3,0,3,2>(acts,b0,u,bh,ssa,ssb,midw); break;
    case 20: k1_body<3,1,3,3>(acts,b0,u,bh,ssa,ssb,midw); break;
    case 21: k1_body<3,2,3,4>(acts,b0,u,bh,ssa,ssb,midw); break;
    default: k1_body<3,3,3,5>(acts,b0,u,bh,ssa,ssb,midw); break;
  }
  atomicAdd(&sumsq[ti*256 + 2*u],     ssa);
  atomicAdd(&sumsq[ti*256 + 2*u + 1], ssb);
}

// ============ K2: scale + build bf16 A matrices (scale folded into W) =======
__global__ __launch_bounds__(256) void k_buildA(const float* __restrict__ W,
                                                const float* __restrict__ bn,
                                                const float* __restrict__ sumsq,
                                                short* __restrict__ A){
  int idx = blockIdx.x*256 + threadIdx.x;   // 5888 channels
  if(idx>=5888) return;
  int l = (idx<1024)?0 : (idx<2560)?1 : (idx<4352)?2 : 3;
  float divi = (l==0)?(1.f/2048.f) : (l==1)?(1.f/6144.f) : (l==2)?(1.f/10240.f) : (1.f/14336.f);
  float bstd = sqrtf(sumsq[idx]*divi);
  float nstd = 0.5f*(bn[idx]+bstd);
  float s = 1.f/(nstd+1e-5f);
  int c = idx - SOFF(l);
  int Ml = MLs(l);
  const float2* wbase = (const float2*)W + WOFF(l) + c;
  unsigned* Aw = (unsigned*)(A + ABASE(l));   // row pitch = Ml words (2*Ml bf16)
  for(int o=0;o<16;++o){
    float2 w = wbase[(size_t)o*Ml];
    Aw[(size_t)o*Ml + c]      = f2bf2(w.x*s, -w.y*s);
    Aw[(size_t)(o+16)*Ml + c] = f2bf2(w.y*s,  w.x*s);
  }
}

// ======== K3: tiled-streaming MFMA GEMM, 4-way K-split ========
// Block = one 16-row n-tile of one l. Wave w streams its contiguous K-quarter:
// per chunk the wave issues ONE 1024B coalesced load (lane-linear tile layout).
// Partials reduced through 6 KB LDS (one barrier), wave 0 stores.
template<int L>
DEVFN void k3_ksplit(int nt, const unsigned* __restrict__ midl,
                     const short* __restrict__ A_l, float* __restrict__ out,
                     float4* __restrict__ red){
  constexpr int NP = 2*L+1;
  constexpr int Ml = MLs(L);
  constexpr int pitchA = 2*Ml;               // bf16 per A row
  constexpr int NK  = Ml/16;                 // K-chunks of 32 bf16 (64/96/112/96)
  constexpr int NKW = NK/4;                  // per-wave chunks (16/24/28/24)
  const int tid = threadIdx.x;
  const int lane = tid & 63, w = tid >> 6;
  const int col = lane & 15, quad = lane >> 4;

  const unsigned* bp = midl + (size_t)nt*((size_t)Ml*16) + (size_t)w*NKW*256 + lane*4;
  const short* a0p = A_l + (size_t)col      *pitchA + quad*8 + w*NKW*32;
  const short* a1p = A_l + (size_t)(col+16) *pitchA + quad*8 + w*NKW*32;

  f32x4 cR = {0.f,0.f,0.f,0.f};
  f32x4 cI = {0.f,0.f,0.f,0.f};
  #pragma unroll 4
  for(int kk=0; kk<NKW; ++kk){
    bf16x8 b  = *(const bf16x8*)(bp  + kk*256);
    bf16x8 a0 = *(const bf16x8*)(a0p + kk*32);
    bf16x8 a1 = *(const bf16x8*)(a1p + kk*32);
    cR = __builtin_amdgcn_mfma_f32_16x16x32_bf16(a0, b, cR, 0, 0, 0);
    cI = __builtin_amdgcn_mfma_f32_16x16x32_bf16(a1, b, cI, 0, 0, 0);
  }
  if(w > 0){
    red[((w-1)*64 + lane)*2]     = make_float4(cR[0],cR[1],cR[2],cR[3]);
    red[((w-1)*64 + lane)*2 + 1] = make_float4(cI[0],cI[1],cI[2],cI[3]);
  }
  __syncthreads();
  if(w == 0){
    #pragma unroll
    for(int j=0;j<3;++j){
      float4 r = red[(j*64+lane)*2], q = red[(j*64+lane)*2+1];
      cR[0]+=r.x; cR[1]+=r.y; cR[2]+=r.z; cR[3]+=r.w;
      cI[0]+=q.x; cI[1]+=q.y; cI[2]+=q.z; cI[3]+=q.w;
    }
    const int n = nt*16 + col;
    const int b = n / NP, p = n % NP;
    float2* out2 = (float2*)out;
    #pragma unroll
    for(int i=0;i<4;++i){
      const int o = quad*4 + i;
      out2[(size_t)b*256 + AOFF(L) + o*NP + p] = make_float2(cR[i], cI[i]);
    }
  }
}

__global__ __launch_bounds__(256) void k_gemm3(const unsigned* __restrict__ midw,
                                               const short* __restrict__ A,
                                               float* __restrict__ out){
  __shared__ float4 red[3*64*2];             // 6 KB
  const int bid = blockIdx.x;                // 2048 = 128(l0)+384(l1)+640(l2)+896(l3)
  if(bid < 128)       k3_ksplit<0>(bid,        midw+MBW(0), A+ABASE(0), out, red);
  else if(bid < 512)  k3_ksplit<1>(bid - 128,  midw+MBW(1), A+ABASE(1), out, red);
  else if(bid < 1152) k3_ksplit<2>(bid - 512,  midw+MBW(2), A+ABASE(2), out, red);
  else                k3_ksplit<3>(bid - 1152, midw+MBW(3), A+ABASE(3), out, red);
}

// ======== fallback (ws too small): recompute-GEMM, unchanged ========
template<int L1,int L2,int L>
DEVFN void phase1(const float2* __restrict__ act2, unsigned* ldsw,
                  int half, int c0, int bh4, int b_lo, int b_hi, int n0){
  constexpr int N1=2*L1+1, N2=2*L2+1, NP=2*L+1;
  const int s  = c0 & 15;
  const int t1 = half*8 + (c0>>4);
  const int t2 = t1 + 4;
  for(int b = b_lo + bh4; b <= b_hi; b += 4){
    const float2* arow = act2 + (size_t)b*256;
    float2 F1a[N1], F1b[N1], F2[N2], mida[NP], midb[NP];
    #pragma unroll
    for(int m=0;m<N1;++m){
      F1a[m]=arow[AOFF(L1)+t1*N1+m];
      F1b[m]=arow[AOFF(L1)+t2*N1+m];
    }
    #pragma unroll
    for(int n=0;n<N2;++n) F2[n]=arow[AOFF(L2)+s*N2+n];
    #pragma unroll
    for(int p=0;p<NP;++p){ mida[p]=make_float2(0.f,0.f); midb[p]=make_float2(0.f,0.f); }
    cg_accum<L1,L2,L>(F1a,F2,mida);
    cg_accum<L1,L2,L>(F1b,F2,midb);
    int nb = b*NP - n0;
    #pragma unroll
    for(int p=0;p<NP;++p){
      int n = nb + p;
      if(n>=0 && n<32){
        ldsw[n*LPITCH + c0]      = f2bf2(mida[p].x, mida[p].y);
        ldsw[n*LPITCH + c0 + 64] = f2bf2(midb[p].x, midb[p].y);
      }
    }
  }
}

template<int L>
DEVFN void p1_dispatch(int q, int half, const float2* __restrict__ act2, unsigned* ldsw,
                       int c0,int bh4,int b_lo,int b_hi,int n0){
  if constexpr(L==0){
    switch(q){
      case 0: phase1<0,0,0>(act2,ldsw,half,c0,bh4,b_lo,b_hi,n0); break;
      case 1: phase1<1,1,0>(act2,ldsw,half,c0,bh4,b_lo,b_hi,n0); break;
      case 2: phase1<2,2,0>(act2,ldsw,half,c0,bh4,b_lo,b_hi,n0); break;
      default:phase1<3,3,0>(act2,ldsw,half,c0,bh4,b_lo,b_hi,n0); break;
    }
  } else if constexpr(L==1){
    switch(q){
      case 0: phase1<1,0,1>(act2,ldsw,half,c0,bh4,b_lo,b_hi,n0); break;
      case 1: phase1<1,1,1>(act2,ldsw,half,c0,bh4,b_lo,b_hi,n0); break;
      case 2: phase1<2,1,1>(act2,ldsw,half,c0,bh4,b_lo,b_hi,n0); break;
      case 3: phase1<2,2,1>(act2,ldsw,half,c0,bh4,b_lo,b_hi,n0); break;
      case 4: phase1<3,2,1>(act2,ldsw,half,c0,bh4,b_lo,b_hi,n0); break;
      default:phase1<3,3,1>(act2,ldsw,half,c0,bh4,b_lo,b_hi,n0); break;
    }
  } else if constexpr(L==2){
    switch(q){
      case 0: phase1<1,1,2>(act2,ldsw,half,c0,bh4,b_lo,b_hi,n0); break;
      case 1: phase1<2,0,2>(act2,ldsw,half,c0,bh4,b_lo,b_hi,n0); break;
      case 2: phase1<2,1,2>(act2,ldsw,half,c0,bh4,b_lo,b_hi,n0); break;
      case 3: phase1<2,2,2>(act2,ldsw,half,c0,bh4,b_lo,b_hi,n0); break;
      case 4: phase1<3,1,2>(act2,ldsw,half,c0,bh4,b_lo,b_hi,n0); break;
      case 5: phase1<3,2,2>(act2,ldsw,half,c0,bh4,b_lo,b_hi,n0); break;
      default:phase1<3,3,2>(act2,ldsw,half,c0,bh4,b_lo,b_hi,n0); break;
    }
  } else {
    switch(q){
      case 0: phase1<2,1,3>(act2,ldsw,half,c0,bh4,b_lo,b_hi,n0); break;
      case 1: phase1<2,2,3>(act2,ldsw,half,c0,bh4,b_lo,b_hi,n0); break;
      case 2: phase1<3,0,3>(act2,ldsw,half,c0,bh4,b_lo,b_hi,n0); break;
      case 3: phase1<3,1,3>(act2,ldsw,half,c0,bh4,b_lo,b_hi,n0); break;
      case 4: phase1<3,2,3>(act2,ldsw,half,c0,bh4,b_lo,b_hi,n0); break;
      default:phase1<3,3,3>(act2,ldsw,half,c0,bh4,b_lo,b_hi,n0); break;
    }
  }
}

template<int L>
DEVFN void k3_gemm(int n0, const float2* __restrict__ act2,
                   const short* __restrict__ A_l, float* __restrict__ out,
                   unsigned* lds){
  constexpr int NP = 2*L+1;
  constexpr int NT = NTRI(L);
  constexpr int pitchA = 2*MLs(L);
  const int tid = threadIdx.x;
  const int lane = tid & 63, wsub = tid >> 6;
  const int col = lane & 15, quad = lane >> 4;
  const int nh = wsub & 1, mh = wsub >> 1;
  const int c0 = tid & 63, bh4 = tid >> 6;
  const int b_lo = n0 / NP;
  const int b_hi = (n0 + 31) / NP;

  f32x4 acc = {0.f,0.f,0.f,0.f};
  const short* Ar = A_l + (size_t)(col + mh*16) * pitchA + quad*8;
  const int lds_rd = (nh*16 + col)*LPITCH + quad*4;

  for(int chunk = 0; chunk < 2*NT; ++chunk){
    const int q = chunk >> 1, half = chunk & 1;
    unsigned* buf = lds + (chunk & 1)*(32*LPITCH);
    p1_dispatch<L>(q, half, act2, buf, c0, bh4, b_lo, b_hi, n0);
    __syncthreads();
    const int kbase = q*512 + half*256;
    const char* ldsb = (const char*)(buf + lds_rd);
    #pragma unroll
    for(int ks=0; ks<8; ++ks){
      bf16x8 a = *(const bf16x8*)(Ar + kbase + ks*32);
      bf16x8 b = *(const bf16x8*)(ldsb + ks*64);
      acc = __builtin_amdgcn_mfma_f32_16x16x32_bf16(a, b, acc, 0, 0, 0);
    }
  }
  const int n = n0 + nh*16 + col;
  const int b = n / NP, p = n % NP;
  #pragma unroll
  for(int i=0;i<4;++i){
    const int o = quad*4 + i;
    out[((size_t)b*256 + AOFF(L) + o*NP + p)*2 + mh] = acc[i];
  }
}

__global__ __launch_bounds__(256) void k_gemm(const float* __restrict__ act,
                                              const short* __restrict__ A,
                                              float* __restrict__ out){
  __shared__ unsigned lds[2*32*LPITCH];
  const int bid = blockIdx.x;
  const float2* act2 = (const float2*)act;
  if(bid < 64)       k3_gemm<0>((bid      )*32, act2, A + ABASE(0), out, lds);
  else if(bid < 256) k3_gemm<1>((bid - 64 )*32, act2, A + ABASE(1), out, lds);
  else if(bid < 576) k3_gemm<2>((bid - 256)*32, act2, A + ABASE(2), out, lds);
  else               k3_gemm<3>((bid - 576)*32, act2, A + ABASE(3), out, lds);
}

// ================= host launch =================
extern "C" void kernel_launch(void* const* d_in, const int* in_sizes, int n_in,
                              void* d_out, int out_size, void* d_ws, size_t ws_size,
                              hipStream_t stream) {
  const float* act = (const float*)d_in[0];   // (2048,256,2) f32
  const float* W   = (const float*)d_in[1];   // (94208,2) f32
  const float* bn  = (const float*)d_in[2];   // (5888,) f32
  float* out = (float*)d_out;                 // (2048,256,2) f32

  float* sumsq = (float*)d_ws;                          // 5888 f32
  short* A     = (short*)((char*)d_ws + 24576);         // 376832 bf16 (754 KB)
  const size_t REQ = (size_t)MID_OFF + MID_BYTES;       // ~209 MB
  unsigned* midw = (ws_size >= REQ) ? (unsigned*)((char*)d_ws + MID_OFF) : nullptr;

  hipMemsetAsync(sumsq, 0, 5888*sizeof(float), stream);
  hipLaunchKernelGGL(k_sumsq,  dim3(23*128), dim3(256), 0, stream, act, sumsq, midw);
  hipLaunchKernelGGL(k_buildA, dim3(23),     dim3(256), 0, stream, W, bn, sumsq, A);
  if(midw)
    hipLaunchKernelGGL(k_gemm3, dim3(2048), dim3(256), 0, stream, (const unsigned*)midw, A, out);
  else
    hipLaunchKernelGGL(k_gemm,  dim3(1024), dim3(256), 0, stream, act, A, out);
}

// Round 9
// 166.549 us; speedup vs baseline: 1.2496x; 1.2496x over previous
//
#include <hip/hip_runtime.h>
#include <math.h>

typedef __attribute__((ext_vector_type(8))) short bf16x8;
typedef __attribute__((ext_vector_type(4))) float f32x4;

// ================= compile-time Clebsch-Gordan tables =================
constexpr double cfact(int n){ double r=1.0; for(int i=2;i<=n;++i) r*=(double)i; return r; }
constexpr double csqrt_(double x){ double g=(x>1.0)?x:1.0; for(int i=0;i<100;++i) g=0.5*(g+x/g); return g; }
constexpr double cg_coef_(int l1,int m1,int l2,int m2,int l,int m){
  double pre = csqrt_((double)(2*l+1)*cfact(l1+l2-l)*cfact(l1-l2+l)*cfact(-l1+l2+l)/cfact(l1+l2+l+1));
  pre = pre*csqrt_(cfact(l+m)*cfact(l-m)*cfact(l1-m1)*cfact(l1+m1)*cfact(l2-m2)*cfact(l2+m2));
  double s=0.0;
  for(int k=0;k<=l1+l2-l;++k){
    int d0=k,d1=l1+l2-l-k,d2=l1-m1-k,d3=l2+m2-k,d4=l-l2+m1+k,d5=l-l1-m2+k;
    if(d0<0||d1<0||d2<0||d3<0||d4<0||d5<0) continue;
    double den=cfact(d0)*cfact(d1)*cfact(d2)*cfact(d3)*cfact(d4)*cfact(d5);
    s+=((k&1)?-1.0:1.0)/den;
  }
  return pre*s;
}
struct CGList{ int n; float coef[64]; int mi[64]; int ni[64]; int pi[64]; };
constexpr CGList build_cg(int l1,int l2,int l){
  CGList T{};
  for(int i=0;i<2*l1+1;++i){
    for(int j=0;j<2*l2+1;++j){
      int m1=i-l1, m2=j-l2, m=m1+m2;
      if(m<-l||m>l) continue;
      double c=cg_coef_(l1,m1,l2,m2,l,m);
      if(c>1e-12||c<-1e-12){
        T.coef[T.n]=(float)c; T.mi[T.n]=i; T.ni[T.n]=j; T.pi[T.n]=m+l; T.n++;
      }
    }
  }
  return T;
}

// ================= layout constants =================
__device__ __host__ constexpr int AOFF(int l){ return l==0?0: l==1?16: l==2?64:144; }
__device__ __host__ constexpr int MLs(int l){ return l==0?1024: l==1?1536: l==2?1792:1536; }
__device__ __host__ constexpr int WOFF(int l){ return l==0?0: l==1?16384: l==2?40960:69632; }
__device__ __host__ constexpr int SOFF(int l){ return l==0?0: l==1?1024: l==2?2560:4352; }
__device__ __host__ constexpr int NTRI(int l){ return l==0?4: l==1?6: l==2?7:6; }
__device__ __host__ constexpr int ABASE(int l){ return l==0?0: l==1?65536: l==2?163840:278528; }
// mid storage (LINEAR): per-l base in 4B words; word = n*Ml + c, n = b*NP+p.
// Writer: coalesced uint2 per wave. Reader: wave-load = 16 full 64B lines.
__device__ __host__ constexpr size_t MBW(int l){ return l==0?0 : l==1?2097152 : l==2?11534336 : 29884416; }
#define MID_OFF 1048576
#define MID_BYTES ((size_t)51904512*4)

#define DEVFN __device__ __forceinline__
#define LPITCH 144   // fallback-path LDS pitch
#define APITCH 132   // gemm4 LDS A-panel row pitch (words): even bank spread

DEVFN unsigned f2bf2(float x, float y){
  unsigned ux = __float_as_uint(x); ux = (ux + 0x7FFFu + ((ux>>16)&1u)) >> 16;
  unsigned uy = __float_as_uint(y); uy = (uy + 0x7FFFu + ((uy>>16)&1u)) >> 16;
  return (ux & 0xFFFFu) | (uy << 16);
}

template<int L1,int L2,int L>
DEVFN void cg_accum(const float2* F1, const float2* F2, float2* mid){
  constexpr CGList T = build_cg(L1,L2,L);
  #pragma unroll
  for(int e=0;e<T.n;++e){
    const float c = T.coef[e];
    const float2 a = F1[T.mi[e]];
    const float2 b = F2[T.ni[e]];
    float pr = a.x*b.x - a.y*b.y;
    float pim= a.x*b.y + a.y*b.x;
    mid[T.pi[e]].x += c*pr;
    mid[T.pi[e]].y += c*pim;
  }
}

// ===== K1: LDS-staged act; channels (2u,2u+1) share F1; coalesced 8B stores =====
template<int L1,int L2,int L,int Q>
DEVFN void k1_body(const float2* __restrict__ acts, int b0, int u, int bh,
                   float& ssa, float& ssb, unsigned* __restrict__ midw){
  constexpr int N1=2*L1+1, N2=2*L2+1, NP=2*L+1, Ml=MLs(L);
  const int t = u>>3, s0 = (u&7)*2;
  unsigned* midq = midw ? (midw + MBW(L) + (size_t)Q*256) : nullptr;
  #pragma unroll 2
  for(int bi=0;bi<8;++bi){
    const int row = bh*8 + bi;
    const float2* arow = acts + row*256;
    float2 F1[N1], F2a[N2], F2b[N2], mida[NP], midb[NP];
    #pragma unroll
    for(int m=0;m<N1;++m) F1[m]=arow[AOFF(L1)+t*N1+m];
    #pragma unroll
    for(int n=0;n<N2;++n){
      F2a[n]=arow[AOFF(L2)+s0*N2+n];
      F2b[n]=arow[AOFF(L2)+(s0+1)*N2+n];
    }
    #pragma unroll
    for(int p=0;p<NP;++p){ mida[p]=make_float2(0.f,0.f); midb[p]=make_float2(0.f,0.f); }
    cg_accum<L1,L2,L>(F1,F2a,mida);
    cg_accum<L1,L2,L>(F1,F2b,midb);
    #pragma unroll
    for(int p=0;p<NP;++p){
      ssa += mida[p].x*mida[p].x + mida[p].y*mida[p].y;
      ssb += midb[p].x*midb[p].x + midb[p].y*midb[p].y;
    }
    if(midq){
      const size_t nrow = (size_t)(b0+row)*NP;
      #pragma unroll
      for(int p=0;p<NP;++p){
        uint2 v; v.x = f2bf2(mida[p].x, mida[p].y); v.y = f2bf2(midb[p].x, midb[p].y);
        ((uint2*)(midq + (nrow+p)*Ml))[u] = v;
      }
    }
  }
}

__global__ __launch_bounds__(256) void k_sumsq(const float* __restrict__ act,
                                               float* __restrict__ sumsq,
                                               unsigned* __restrict__ midw){
  __shared__ float2 acts[16*256];            // 32 KB: 16 act rows
  int bid=blockIdx.x;                        // 23 triples * 128 chunks
  const int order[23] = {22,16,21,18,15,20,13,9,14,8,17,7,12,6,10,3,5,19,2,11,1,4,0};
  int ti = order[bid>>7];
  int b0 = (bid&127)*16;
  const int tid = threadIdx.x;
  {
    const float4* ag = (const float4*)act + (size_t)b0*128;
    float4* as4 = (float4*)acts;
    #pragma unroll
    for(int j=0;j<8;++j) as4[j*256+tid] = ag[j*256+tid];
  }
  __syncthreads();
  const int u = tid & 127, bh = tid >> 7;    // channels (2u,2u+1), b-half bh
  float ssa=0.f, ssb=0.f;
  switch(ti){
    case 0:  k1_body<0,0,0,0>(acts,b0,u,bh,ssa,ssb,midw); break;
    case 1:  k1_body<1,1,0,1>(acts,b0,u,bh,ssa,ssb,midw); break;
    case 2:  k1_body<2,2,0,2>(acts,b0,u,bh,ssa,ssb,midw); break;
    case 3:  k1_body<3,3,0,3>(acts,b0,u,bh,ssa,ssb,midw); break;
    case 4:  k1_body<1,0,1,0>(acts,b0,u,bh,ssa,ssb,midw); break;
    case 5:  k1_body<1,1,1,1>(acts,b0,u,bh,ssa,ssb,midw); break;
    case 6:  k1_body<2,1,1,2>(acts,b0,u,bh,ssa,ssb,midw); break;
    case 7:  k1_body<2,2,1,3>(acts,b0,u,bh,ssa,ssb,midw); break;
    case 8:  k1_body<3,2,1,4>(acts,b0,u,bh,ssa,ssb,midw); break;
    case 9:  k1_body<3,3,1,5>(acts,b0,u,bh,ssa,ssb,midw); break;
    case 10: k1_body<1,1,2,0>(acts,b0,u,bh,ssa,ssb,midw); break;
    case 11: k1_body<2,0,2,1>(acts,b0,u,bh,ssa,ssb,midw); break;
    case 12: k1_body<2,1,2,2>(acts,b0,u,bh,ssa,ssb,midw); break;
    case 13: k1_body<2,2,2,3>(acts,b0,u,bh,ssa,ssb,midw); break;
    case 14: k1_body<3,1,2,4>(acts,b0,u,bh,ssa,ssb,midw); break;
    case 15: k1_body<3,2,2,5>(acts,b0,u,bh,ssa,ssb,midw); break;
    case 16: k1_body<3,3,2,6>(acts,b0,u,bh,ssa,ssb,midw); break;
    case 17: k1_body<2,1,3,0>(acts,b0,u,bh,ssa,ssb,midw); break;
    case 18: k1_body<2,2,3,1>(acts,b0,u,bh,ssa,ssb,midw); break;
    case 19: k1_body<3,0,3,2>(acts,b0,u,bh,ssa,ssb,midw); break;
    case 20: k1_body<3,1,3,3>(acts,b0,u,bh,ssa,ssb,midw); break;
    case 21: k1_body<3,2,3,4>(acts,b0,u,bh,ssa,ssb,midw); break;
    default: k1_body<3,3,3,5>(acts,b0,u,bh,ssa,ssb,midw); break;
  }
  atomicAdd(&sumsq[ti*256 + 2*u],     ssa);
  atomicAdd(&sumsq[ti*256 + 2*u + 1], ssb);
}

// ============ K2: scale + build bf16 A matrices (scale folded into W) =======
__global__ __launch_bounds__(256) void k_buildA(const float* __restrict__ W,
                                                const float* __restrict__ bn,
                                                const float* __restrict__ sumsq,
                                                short* __restrict__ A){
  int idx = blockIdx.x*256 + threadIdx.x;   // 5888 channels
  if(idx>=5888) return;
  int l = (idx<1024)?0 : (idx<2560)?1 : (idx<4352)?2 : 3;
  float divi = (l==0)?(1.f/2048.f) : (l==1)?(1.f/6144.f) : (l==2)?(1.f/10240.f) : (1.f/14336.f);
  float bstd = sqrtf(sumsq[idx]*divi);
  float nstd = 0.5f*(bn[idx]+bstd);
  float s = 1.f/(nstd+1e-5f);
  int c = idx - SOFF(l);
  int Ml = MLs(l);
  const float2* wbase = (const float2*)W + WOFF(l) + c;
  unsigned* Aw = (unsigned*)(A + ABASE(l));   // row pitch = Ml words (2*Ml bf16)
  for(int o=0;o<16;++o){
    float2 w = wbase[(size_t)o*Ml];
    Aw[(size_t)o*Ml + c]      = f2bf2(w.x*s, -w.y*s);
    Aw[(size_t)(o+16)*Ml + c] = f2bf2(w.y*s,  w.x*s);
  }
}

// ======== K4: panel-staged MFMA GEMM — A read ONCE per block ========
// Block (512 thr, 8 waves) = 8 n-tiles × full K of one l. A K-panels
// (256 k-cols = 16 KB) double-buffered in LDS (pitch 132 words -> even
// banks); one barrier per panel. B streams direct from global (linear
// mid layout = MFMA B-fragment layout; 16 full lines per wave-load).
template<int L>
DEVFN void k4_panel(int tg, const unsigned* __restrict__ midl,
                    const short* __restrict__ A_l, float* __restrict__ out,
                    unsigned* ldsA){
  constexpr int NP = 2*L+1;
  constexpr int Ml = MLs(L);
  constexpr int NK = Ml/16;                  // 32-k chunks (64/96/112/96)
  constexpr int P  = NK/8;                   // panels (8/12/14/12)
  const int tid = threadIdx.x;               // 0..511
  const int lane = tid & 63, w = tid >> 6;
  const int col = lane & 15, quad = lane >> 4;
  const int nt = tg*8 + w;
  const unsigned* Aw = (const unsigned*)A_l;             // word view, pitch Ml
  const unsigned* bp = midl + (size_t)(nt*16 + col)*Ml + quad*4;

  // staging slots: thread covers 16B at (r0,j0) and (r1,j1) of the panel
  const int r0 = tid >> 5,        j0 = (tid & 31)*4;     // rows 0..15
  const int r1 = (tid+512) >> 5,  j1 = j0;               // rows 16..31

  f32x4 cR = {0.f,0.f,0.f,0.f};
  f32x4 cI = {0.f,0.f,0.f,0.f};
  {
    uint4 v0 = *(const uint4*)(Aw + (size_t)r0*Ml + j0);
    uint4 v1 = *(const uint4*)(Aw + (size_t)r1*Ml + j1);
    *(uint4*)(ldsA + r0*APITCH + j0) = v0;
    *(uint4*)(ldsA + r1*APITCH + j1) = v1;
  }
  __syncthreads();
  for(int p=0; p<P; ++p){
    const unsigned* buf  = ldsA + (p&1)*(32*APITCH);
    unsigned* nbuf = ldsA + ((p+1)&1)*(32*APITCH);
    uint4 v0, v1;
    if(p+1 < P){
      v0 = *(const uint4*)(Aw + (size_t)r0*Ml + (p+1)*128 + j0);
      v1 = *(const uint4*)(Aw + (size_t)r1*Ml + (p+1)*128 + j1);
    }
    const unsigned* bpp = bp + p*128;
    const unsigned* a0 = buf + col*APITCH + quad*4;
    const unsigned* a1 = buf + (col+16)*APITCH + quad*4;
    #pragma unroll
    for(int c=0; c<8; ++c){
      bf16x8 b  = *(const bf16x8*)(bpp + c*16);
      bf16x8 A0 = *(const bf16x8*)(a0 + c*16);
      bf16x8 A1 = *(const bf16x8*)(a1 + c*16);
      cR = __builtin_amdgcn_mfma_f32_16x16x32_bf16(A0, b, cR, 0, 0, 0);
      cI = __builtin_amdgcn_mfma_f32_16x16x32_bf16(A1, b, cI, 0, 0, 0);
    }
    if(p+1 < P){
      *(uint4*)(nbuf + r0*APITCH + j0) = v0;
      *(uint4*)(nbuf + r1*APITCH + j1) = v1;
    }
    __syncthreads();
  }
  const int n = nt*16 + col;
  const int b = n / NP, pp = n % NP;
  float2* out2 = (float2*)out;
  #pragma unroll
  for(int i=0;i<4;++i){
    const int o = quad*4 + i;
    out2[(size_t)b*256 + AOFF(L) + o*NP + pp] = make_float2(cR[i], cI[i]);
  }
}

__global__ __launch_bounds__(512) void k_gemm4(const unsigned* __restrict__ midw,
                                               const short* __restrict__ A,
                                               float* __restrict__ out){
  __shared__ unsigned ldsA[2*32*APITCH];     // 33792 B dbuf
  const int bid = blockIdx.x;                // 256 = 16(l0)+48(l1)+80(l2)+112(l3)
  if(bid < 16)       k4_panel<0>(bid,       midw+MBW(0), A+ABASE(0), out, ldsA);
  else if(bid < 64)  k4_panel<1>(bid - 16,  midw+MBW(1), A+ABASE(1), out, ldsA);
  else if(bid < 144) k4_panel<2>(bid - 64,  midw+MBW(2), A+ABASE(2), out, ldsA);
  else               k4_panel<3>(bid - 144, midw+MBW(3), A+ABASE(3), out, ldsA);
}

// ======== fallback (ws too small): recompute-GEMM, unchanged ========
template<int L1,int L2,int L>
DEVFN void phase1(const float2* __restrict__ act2, unsigned* ldsw,
                  int half, int c0, int bh4, int b_lo, int b_hi, int n0){
  constexpr int N1=2*L1+1, N2=2*L2+1, NP=2*L+1;
  const int s  = c0 & 15;
  const int t1 = half*8 + (c0>>4);
  const int t2 = t1 + 4;
  for(int b = b_lo + bh4; b <= b_hi; b += 4){
    const float2* arow = act2 + (size_t)b*256;
    float2 F1a[N1], F1b[N1], F2[N2], mida[NP], midb[NP];
    #pragma unroll
    for(int m=0;m<N1;++m){
      F1a[m]=arow[AOFF(L1)+t1*N1+m];
      F1b[m]=arow[AOFF(L1)+t2*N1+m];
    }
    #pragma unroll
    for(int n=0;n<N2;++n) F2[n]=arow[AOFF(L2)+s*N2+n];
    #pragma unroll
    for(int p=0;p<NP;++p){ mida[p]=make_float2(0.f,0.f); midb[p]=make_float2(0.f,0.f); }
    cg_accum<L1,L2,L>(F1a,F2,mida);
    cg_accum<L1,L2,L>(F1b,F2,midb);
    int nb = b*NP - n0;
    #pragma unroll
    for(int p=0;p<NP;++p){
      int n = nb + p;
      if(n>=0 && n<32){
        ldsw[n*LPITCH + c0]      = f2bf2(mida[p].x, mida[p].y);
        ldsw[n*LPITCH + c0 + 64] = f2bf2(midb[p].x, midb[p].y);
      }
    }
  }
}

template<int L>
DEVFN void p1_dispatch(int q, int half, const float2* __restrict__ act2, unsigned* ldsw,
                       int c0,int bh4,int b_lo,int b_hi,int n0){
  if constexpr(L==0){
    switch(q){
      case 0: phase1<0,0,0>(act2,ldsw,half,c0,bh4,b_lo,b_hi,n0); break;
      case 1: phase1<1,1,0>(act2,ldsw,half,c0,bh4,b_lo,b_hi,n0); break;
      case 2: phase1<2,2,0>(act2,ldsw,half,c0,bh4,b_lo,b_hi,n0); break;
      default:phase1<3,3,0>(act2,ldsw,half,c0,bh4,b_lo,b_hi,n0); break;
    }
  } else if constexpr(L==1){
    switch(q){
      case 0: phase1<1,0,1>(act2,ldsw,half,c0,bh4,b_lo,b_hi,n0); break;
      case 1: phase1<1,1,1>(act2,ldsw,half,c0,bh4,b_lo,b_hi,n0); break;
      case 2: phase1<2,1,1>(act2,ldsw,half,c0,bh4,b_lo,b_hi,n0); break;
      case 3: phase1<2,2,1>(act2,ldsw,half,c0,bh4,b_lo,b_hi,n0); break;
      case 4: phase1<3,2,1>(act2,ldsw,half,c0,bh4,b_lo,b_hi,n0); break;
      default:phase1<3,3,1>(act2,ldsw,half,c0,bh4,b_lo,b_hi,n0); break;
    }
  } else if constexpr(L==2){
    switch(q){
      case 0: phase1<1,1,2>(act2,ldsw,half,c0,bh4,b_lo,b_hi,n0); break;
      case 1: phase1<2,0,2>(act2,ldsw,half,c0,bh4,b_lo,b_hi,n0); break;
      case 2: phase1<2,1,2>(act2,ldsw,half,c0,bh4,b_lo,b_hi,n0); break;
      case 3: phase1<2,2,2>(act2,ldsw,half,c0,bh4,b_lo,b_hi,n0); break;
      case 4: phase1<3,1,2>(act2,ldsw,half,c0,bh4,b_lo,b_hi,n0); break;
      case 5: phase1<3,2,2>(act2,ldsw,half,c0,bh4,b_lo,b_hi,n0); break;
      default:phase1<3,3,2>(act2,ldsw,half,c0,bh4,b_lo,b_hi,n0); break;
    }
  } else {
    switch(q){
      case 0: phase1<2,1,3>(act2,ldsw,half,c0,bh4,b_lo,b_hi,n0); break;
      case 1: phase1<2,2,3>(act2,ldsw,half,c0,bh4,b_lo,b_hi,n0); break;
      case 2: phase1<3,0,3>(act2,ldsw,half,c0,bh4,b_lo,b_hi,n0); break;
      case 3: phase1<3,1,3>(act2,ldsw,half,c0,bh4,b_lo,b_hi,n0); break;
      case 4: phase1<3,2,3>(act2,ldsw,half,c0,bh4,b_lo,b_hi,n0); break;
      default:phase1<3,3,3>(act2,ldsw,half,c0,bh4,b_lo,b_hi,n0); break;
    }
  }
}

template<int L>
DEVFN void k3_gemm(int n0, const float2* __restrict__ act2,
                   const short* __restrict__ A_l, float* __restrict__ out,
                   unsigned* lds){
  constexpr int NP = 2*L+1;
  constexpr int NT = NTRI(L);
  constexpr int pitchA = 2*MLs(L);
  const int tid = threadIdx.x;
  const int lane = tid & 63, wsub = tid >> 6;
  const int col = lane & 15, quad = lane >> 4;
  const int nh = wsub & 1, mh = wsub >> 1;
  const int c0 = tid & 63, bh4 = tid >> 6;
  const int b_lo = n0 / NP;
  const int b_hi = (n0 + 31) / NP;

  f32x4 acc = {0.f,0.f,0.f,0.f};
  const short* Ar = A_l + (size_t)(col + mh*16) * pitchA + quad*8;
  const int lds_rd = (nh*16 + col)*LPITCH + quad*4;

  for(int chunk = 0; chunk < 2*NT; ++chunk){
    const int q = chunk >> 1, half = chunk & 1;
    unsigned* buf = lds + (chunk & 1)*(32*LPITCH);
    p1_dispatch<L>(q, half, act2, buf, c0, bh4, b_lo, b_hi, n0);
    __syncthreads();
    const int kbase = q*512 + half*256;
    const char* ldsb = (const char*)(buf + lds_rd);
    #pragma unroll
    for(int ks=0; ks<8; ++ks){
      bf16x8 a = *(const bf16x8*)(Ar + kbase + ks*32);
      bf16x8 b = *(const bf16x8*)(ldsb + ks*64);
      acc = __builtin_amdgcn_mfma_f32_16x16x32_bf16(a, b, acc, 0, 0, 0);
    }
  }
  const int n = n0 + nh*16 + col;
  const int b = n / NP, p = n % NP;
  #pragma unroll
  for(int i=0;i<4;++i){
    const int o = quad*4 + i;
    out[((size_t)b*256 + AOFF(L) + o*NP + p)*2 + mh] = acc[i];
  }
}

__global__ __launch_bounds__(256) void k_gemm(const float* __restrict__ act,
                                              const short* __restrict__ A,
                                              float* __restrict__ out){
  __shared__ unsigned lds[2*32*LPITCH];
  const int bid = blockIdx.x;
  const float2* act2 = (const float2*)act;
  if(bid < 64)       k3_gemm<0>((bid      )*32, act2, A + ABASE(0), out, lds);
  else if(bid < 256) k3_gemm<1>((bid - 64 )*32, act2, A + ABASE(1), out, lds);
  else if(bid < 576) k3_gemm<2>((bid - 256)*32, act2, A + ABASE(2), out, lds);
  else               k3_gemm<3>((bid - 576)*32, act2, A + ABASE(3), out, lds);
}

// ================= host launch =================
extern "C" void kernel_launch(void* const* d_in, const int* in_sizes, int n_in,
                              void* d_out, int out_size, void* d_ws, size_t ws_size,
                              hipStream_t stream) {
  const float* act = (const float*)d_in[0];   // (2048,256,2) f32
  const float* W   = (const float*)d_in[1];   // (94208,2) f32
  const float* bn  = (const float*)d_in[2];   // (5888,) f32
  float* out = (float*)d_out;                 // (2048,256,2) f32

  float* sumsq = (float*)d_ws;                          // 5888 f32
  short* A     = (short*)((char*)d_ws + 24576);         // 376832 bf16 (754 KB)
  const size_t REQ = (size_t)MID_OFF + MID_BYTES;       // ~209 MB
  unsigned* midw = (ws_size >= REQ) ? (unsigned*)((char*)d_ws + MID_OFF) : nullptr;

  hipMemsetAsync(sumsq, 0, 5888*sizeof(float), stream);
  hipLaunchKernelGGL(k_sumsq,  dim3(23*128), dim3(256), 0, stream, act, sumsq, midw);
  hipLaunchKernelGGL(k_buildA, dim3(23),     dim3(256), 0, stream, W, bn, sumsq, A);
  if(midw)
    hipLaunchKernelGGL(k_gemm4, dim3(256),  dim3(512), 0, stream, (const unsigned*)midw, A, out);
  else
    hipLaunchKernelGGL(k_gemm,  dim3(1024), dim3(256), 0, stream, act, A, out);
}